// Round 4
// baseline (60833.484 us; speedup 1.0000x reference)
//
#include <hip/hip_runtime.h>
#include <hip/hip_bf16.h>
#include <math.h>

#define B_   128
#define T_   256
#define IN_  512
#define C_   2048
#define N_   256
#define M_   128
#define OUT_ 512
#define PR   134          // M_+6
#define PWW  390          // 3M+6
#define PTOT 1036         // PR + PWW + OUT_
#define EPSF 1e-8f

__device__ __forceinline__ float softplusf(float x) { return (x > 20.f) ? x : log1pf(expf(x)); }
__device__ __forceinline__ float sigmoidf(float x) { return 1.f / (1.f + expf(-x)); }

// ---------------- init ----------------
__global__ __launch_bounds__(256) void init_state(
    float* __restrict__ mem, float* __restrict__ w_r, float* __restrict__ w_w,
    float* __restrict__ r,
    const float* __restrict__ mem_init, const float* __restrict__ read_init)
{
    int i0 = blockIdx.x * blockDim.x + threadIdx.x;
    int stride = gridDim.x * blockDim.x;
    for (int i = i0; i < B_ * N_ * M_; i += stride)
        mem[i] = mem_init[i & (N_ * M_ - 1)];
    for (int i = i0; i < B_ * N_; i += stride) { w_r[i] = 1.f / N_; w_w[i] = 1.f / N_; }
    for (int i = i0; i < B_ * M_; i += stride) r[i] = read_init[i & (M_ - 1)];
}

// ---------------- h = tanh(cat(r, x_t) @ Wc + bc) ----------------
__global__ __launch_bounds__(256) void gemm_h_naive(
    const float* __restrict__ r, const float* __restrict__ x,
    const float* __restrict__ Wc, const float* __restrict__ bc,
    float* __restrict__ h, int t)
{
    int idx = blockIdx.x * 256 + threadIdx.x;
    int row = idx >> 11;          // / C_
    int col = idx & (C_ - 1);
    const float* xr = x + ((size_t)row * T_ + t) * IN_;
    const float* rr = r + row * M_;
    float acc = bc[col];
    for (int k = 0; k < M_; k++)  acc += rr[k] * Wc[(size_t)k * C_ + col];
    for (int k = 0; k < IN_; k++) acc += xr[k] * Wc[(size_t)(M_ + k) * C_ + col];
    h[idx] = tanhf(acc);
}

// ---------------- P = h @ [Wr | Ww | Wout] + [br | bw | bout]; also writes out ----------------
__global__ __launch_bounds__(256) void gemm_p_naive(
    const float* __restrict__ h,
    const float* __restrict__ Wr, const float* __restrict__ br,
    const float* __restrict__ Ww, const float* __restrict__ bw,
    const float* __restrict__ Wout, const float* __restrict__ bout,
    float* __restrict__ P, float* __restrict__ out, int t)
{
    int row = blockIdx.y;
    int col = blockIdx.x * 256 + threadIdx.x;
    if (col >= PTOT) return;
    const float* W; const float* bias; int ld, jc;
    if (col < PR)            { W = Wr;   bias = br;   ld = PR;   jc = col; }
    else if (col < PR + PWW) { W = Ww;   bias = bw;   ld = PWW;  jc = col - PR; }
    else                     { W = Wout; bias = bout; ld = OUT_; jc = col - PR - PWW; }
    const float* hr = h + (size_t)row * C_;
    float acc = bias[jc];
    for (int k = 0; k < C_; k++) acc += hr[k] * W[(size_t)k * ld + jc];
    P[(size_t)row * PTOT + col] = acc;
    if (col >= PR + PWW)
        out[((size_t)row * T_ + t) * OUT_ + jc] = acc;   // fp32 output
}

// ---------------- addressing ----------------
struct __align__(16) AddrShared {
    float p_sh[136];
    float red[256];
    float wsh[256];
    float scal[8];
    float ea[256];
};

__device__ __forceinline__ void compute_w(
    AddrShared& sm, const float* __restrict__ P,
    const float* __restrict__ mem, float* __restrict__ wglob, int b, int poff)
{
    int tid = threadIdx.x;
    if (tid < PR) sm.p_sh[tid] = P[(size_t)b * PTOT + poff + tid];
    __syncthreads();
    // ||k||^2
    float kq = 0.f;
    if (tid < M_) { float kv = sm.p_sh[tid]; kq = kv * kv; }
    sm.red[tid] = kq;
    __syncthreads();
    for (int s = 128; s > 0; s >>= 1) { if (tid < s) sm.red[tid] += sm.red[tid + s]; __syncthreads(); }
    if (tid == 0) {
        sm.scal[0] = sqrtf(sm.red[0]);                 // ||k||
        sm.scal[1] = softplusf(sm.p_sh[M_]);           // beta
        sm.scal[2] = sigmoidf(sm.p_sh[M_ + 1]);        // g
        float a0 = sm.p_sh[M_ + 2], a1 = sm.p_sh[M_ + 3], a2 = sm.p_sh[M_ + 4];
        float mx = fmaxf(a0, fmaxf(a1, a2));
        float e0 = expf(a0 - mx), e1 = expf(a1 - mx), e2 = expf(a2 - mx);
        float inv = 1.f / (e0 + e1 + e2);
        sm.scal[3] = e0 * inv; sm.scal[4] = e1 * inv; sm.scal[5] = e2 * inv;  // s
        sm.scal[6] = 1.f + softplusf(sm.p_sh[M_ + 5]); // gamma
    }
    __syncthreads();
    // cosine similarity, one memory row n per thread
    const float* mrow = mem + ((size_t)b * N_ + tid) * M_;
    float dot = 0.f, nrm = 0.f;
#pragma unroll 8
    for (int m = 0; m < M_; m += 4) {
        float4 v = *(const float4*)&mrow[m];
        float4 kk = *(const float4*)&sm.p_sh[m];
        dot += v.x * kk.x + v.y * kk.y + v.z * kk.z + v.w * kk.w;
        nrm += v.x * v.x + v.y * v.y + v.z * v.z + v.w * v.w;
    }
    float sim = dot / (sm.scal[0] * sqrtf(nrm) + EPSF);
    float zz = sm.scal[1] * sim;
    // softmax over n
    sm.red[tid] = zz;
    __syncthreads();
    for (int s = 128; s > 0; s >>= 1) { if (tid < s) sm.red[tid] = fmaxf(sm.red[tid], sm.red[tid + s]); __syncthreads(); }
    float mx = sm.red[0];
    __syncthreads();
    float ez = expf(zz - mx);
    sm.red[tid] = ez;
    __syncthreads();
    for (int s = 128; s > 0; s >>= 1) { if (tid < s) sm.red[tid] += sm.red[tid + s]; __syncthreads(); }
    float wc = ez / sm.red[0];
    float g = sm.scal[2];
    float wgv = g * wc + (1.f - g) * wglob[(size_t)b * N_ + tid];
    __syncthreads();
    sm.wsh[tid] = wgv;
    __syncthreads();
    // wt[n] = s0*wg[n+1] + s1*wg[n] + s2*wg[n-1] (circular)
    float wt = sm.scal[3] * sm.wsh[(tid + 1) & (N_ - 1)]
             + sm.scal[4] * wgv
             + sm.scal[5] * sm.wsh[(tid + N_ - 1) & (N_ - 1)];
    float wp = powf(wt + EPSF, sm.scal[6]);
    sm.red[tid] = wp;
    __syncthreads();
    for (int s = 128; s > 0; s >>= 1) { if (tid < s) sm.red[tid] += sm.red[tid + s]; __syncthreads(); }
    float wfin = wp / sm.red[0];
    wglob[(size_t)b * N_ + tid] = wfin;
    __syncthreads();
    sm.wsh[tid] = wfin;
    __syncthreads();
}

__global__ __launch_bounds__(256) void addr_read_kernel(
    const float* __restrict__ P, const float* __restrict__ mem,
    float* __restrict__ w_r, float* __restrict__ r_out)
{
    __shared__ AddrShared sm;
    int b = blockIdx.x, tid = threadIdx.x;
    compute_w(sm, P, mem, w_r, b, 0);
    if (tid < M_) {
        float acc = 0.f;
        const float* mb = mem + (size_t)b * N_ * M_;
        for (int n = 0; n < N_; n++) acc += sm.wsh[n] * mb[n * M_ + tid];
        r_out[b * M_ + tid] = acc;
    }
}

__global__ __launch_bounds__(256) void addr_write_kernel(
    const float* __restrict__ P, float* __restrict__ mem, float* __restrict__ w_w)
{
    __shared__ AddrShared sm;
    int b = blockIdx.x, tid = threadIdx.x;
    compute_w(sm, P, mem, w_w, b, PR);
    if (tid < M_) {
        sm.ea[tid]      = sigmoidf(P[(size_t)b * PTOT + 2 * PR + tid]);        // e, cols 268..395
        sm.ea[M_ + tid] = tanhf(P[(size_t)b * PTOT + 2 * PR + M_ + tid]);      // a, cols 396..523
    }
    __syncthreads();
    float* mb = mem + (size_t)b * N_ * M_;
    for (int idx = tid; idx < N_ * M_; idx += 256) {
        int n = idx >> 7, m = idx & (M_ - 1);
        float wv = sm.wsh[n];
        mb[idx] = mb[idx] * (1.f - wv * sm.ea[m]) + wv * sm.ea[M_ + m];
    }
}

// ---------------- launch ----------------
static const float* by_size(void* const* d_in, const int* in_sizes, int n_in,
                            long long want, int fallback)
{
    for (int i = 0; i < n_in; i++)
        if ((long long)in_sizes[i] == want) return (const float*)d_in[i];
    return (const float*)d_in[fallback];
}

extern "C" void kernel_launch(void* const* d_in, const int* in_sizes, int n_in,
                              void* d_out, int out_size, void* d_ws, size_t ws_size,
                              hipStream_t stream)
{
    const float* x         = by_size(d_in, in_sizes, n_in, (long long)B_ * T_ * IN_, 0);
    const float* Wc        = by_size(d_in, in_sizes, n_in, (long long)(M_ + IN_) * C_, 1);
    const float* bc        = by_size(d_in, in_sizes, n_in, C_, 2);
    const float* Wout      = by_size(d_in, in_sizes, n_in, (long long)C_ * OUT_, 3);
    const float* bout      = by_size(d_in, in_sizes, n_in, OUT_, 4);
    const float* Wr        = by_size(d_in, in_sizes, n_in, (long long)C_ * PR, 5);
    const float* br        = by_size(d_in, in_sizes, n_in, PR, 6);
    const float* Ww        = by_size(d_in, in_sizes, n_in, (long long)C_ * PWW, 7);
    const float* bw        = by_size(d_in, in_sizes, n_in, PWW, 8);
    const float* mem_init  = by_size(d_in, in_sizes, n_in, N_ * M_, 9);
    const float* read_init = by_size(d_in, in_sizes, n_in, M_, 10);
    float* out = (float*)d_out;

    char* p = (char*)d_ws;
    auto alloc = [&](size_t bytes) -> void* {
        void* q = (void*)p;
        p += (bytes + 255) & ~(size_t)255;
        return q;
    };
    float* mem = (float*)alloc(sizeof(float) * B_ * N_ * M_);
    float* r   = (float*)alloc(sizeof(float) * B_ * M_);
    float* w_r = (float*)alloc(sizeof(float) * B_ * N_);
    float* w_w = (float*)alloc(sizeof(float) * B_ * N_);
    float* h   = (float*)alloc(sizeof(float) * B_ * C_);
    float* P   = (float*)alloc(sizeof(float) * B_ * PTOT);

    init_state<<<2048, 256, 0, stream>>>(mem, w_r, w_w, r, mem_init, read_init);

    for (int t = 0; t < T_; t++) {
        gemm_h_naive<<<(B_ * C_) / 256, 256, 0, stream>>>(r, x, Wc, bc, h, t);
        gemm_p_naive<<<dim3(5, B_), 256, 0, stream>>>(h, Wr, br, Ww, bw, Wout, bout, P, out, t);
        addr_read_kernel<<<128, 256, 0, stream>>>(P, mem, w_r, r);
        addr_write_kernel<<<128, 256, 0, stream>>>(P, mem, w_w);
    }
}

// Round 5
// 38543.228 us; speedup vs baseline: 1.5783x; 1.5783x over previous
//
#include <hip/hip_runtime.h>
#include <hip/hip_bf16.h>
#include <math.h>

#define B_   128
#define T_   256
#define IN_  512
#define C_   2048
#define N_   256
#define M_   128
#define OUT_ 512
#define PR   134          // M_+6
#define PWW  390          // 3M+6
#define PTOT 1036         // PR + PWW + OUT_
#define EPSF 1e-8f

__device__ __forceinline__ float softplusf(float x) { return (x > 20.f) ? x : log1pf(expf(x)); }
__device__ __forceinline__ float sigmoidf(float x) { return 1.f / (1.f + expf(-x)); }

// ---------------- init: state + concatenated bias ----------------
__global__ __launch_bounds__(256) void init_state(
    float* __restrict__ mem, float* __restrict__ w_r, float* __restrict__ w_w,
    float* __restrict__ r, float* __restrict__ bcat,
    const float* __restrict__ mem_init, const float* __restrict__ read_init,
    const float* __restrict__ br, const float* __restrict__ bw, const float* __restrict__ bout)
{
    int i0 = blockIdx.x * blockDim.x + threadIdx.x;
    int stride = gridDim.x * blockDim.x;
    for (int i = i0; i < B_ * N_ * M_; i += stride)
        mem[i] = mem_init[i & (N_ * M_ - 1)];
    for (int i = i0; i < B_ * N_; i += stride) { w_r[i] = 1.f / N_; w_w[i] = 1.f / N_; }
    for (int i = i0; i < B_ * M_; i += stride) r[i] = read_init[i & (M_ - 1)];
    for (int i = i0; i < PTOT; i += stride)
        bcat[i] = (i < PR) ? br[i] : (i < PR + PWW) ? bw[i - PR] : bout[i - PR - PWW];
}

// ---------------- GEMM 1: Hpart[z] = cat(r, x_t) @ Wc  (64x64 tile, split-K=4) ----------------
// grid (32, 2, 4)
__global__ __launch_bounds__(256) void gemm_h_tiled(
    const float* __restrict__ r, const float* __restrict__ x,
    const float* __restrict__ Wc, float* __restrict__ Hpart, int t)
{
    const int KS = 160;
    int z = blockIdx.z;
    int row0 = blockIdx.y * 64, col0 = blockIdx.x * 64;
    __shared__ __align__(16) float As[16][68];
    __shared__ __align__(16) float Bs[16][68];
    int tid = threadIdx.x;
    int tx = tid & 15, ty = tid >> 4;
    float acc[4][4];
#pragma unroll
    for (int i = 0; i < 4; i++)
#pragma unroll
        for (int j = 0; j < 4; j++) acc[i][j] = 0.f;

    int k0base = z * KS;
    for (int k0 = k0base; k0 < k0base + KS; k0 += 16) {
#pragma unroll
        for (int l = 0; l < 4; l++) {
            int e = tid + l * 256;
            int rr = e >> 4, kk = e & 15;
            int gr = row0 + rr, gk = k0 + kk;
            float v;
            if (gk < M_) v = r[gr * M_ + gk];
            else v = x[((size_t)gr * T_ + t) * IN_ + (gk - M_)];
            As[kk][rr] = v;
        }
#pragma unroll
        for (int l = 0; l < 4; l++) {
            int e = tid + l * 256;
            int kk = e >> 6, cc = e & 63;
            Bs[kk][cc] = Wc[(size_t)(k0 + kk) * C_ + col0 + cc];
        }
        __syncthreads();
#pragma unroll
        for (int kk = 0; kk < 16; kk++) {
            float4 a4 = *(const float4*)&As[kk][ty * 4];
            float4 b4 = *(const float4*)&Bs[kk][tx * 4];
            float av[4] = {a4.x, a4.y, a4.z, a4.w};
            float bv[4] = {b4.x, b4.y, b4.z, b4.w};
#pragma unroll
            for (int i = 0; i < 4; i++)
#pragma unroll
                for (int j = 0; j < 4; j++) acc[i][j] += av[i] * bv[j];
        }
        __syncthreads();
    }
    float* Hp = Hpart + (size_t)z * B_ * C_;
#pragma unroll
    for (int i = 0; i < 4; i++)
#pragma unroll
        for (int j = 0; j < 4; j++)
            Hp[(size_t)(row0 + ty * 4 + i) * C_ + col0 + tx * 4 + j] = acc[i][j];
}

// ---------------- finalize h = tanh(sum of 4 partials + bc) ----------------
__global__ __launch_bounds__(256) void finalize_h(
    const float* __restrict__ Hpart, const float* __restrict__ bc, float* __restrict__ h)
{
    int i = blockIdx.x * 256 + threadIdx.x;
    float v = Hpart[i] + Hpart[B_ * C_ + i] + Hpart[2 * B_ * C_ + i] + Hpart[3 * B_ * C_ + i]
            + bc[i & (C_ - 1)];
    h[i] = tanhf(v);
}

// ---------------- GEMM 2: Ppart[z] = h @ [Wr|Ww|Wout]  (64x64 tile, split-K=4) ----------------
// grid (17, 2, 4)
__global__ __launch_bounds__(256) void gemm_p_tiled(
    const float* __restrict__ h,
    const float* __restrict__ Wr, const float* __restrict__ Ww, const float* __restrict__ Wout,
    float* __restrict__ Ppart)
{
    const int KS = 512;
    int z = blockIdx.z;
    int row0 = blockIdx.y * 64, col0 = blockIdx.x * 64;
    __shared__ __align__(16) float As[16][68];
    __shared__ __align__(16) float Bs[16][68];
    int tid = threadIdx.x;
    int tx = tid & 15, ty = tid >> 4;
    float acc[4][4];
#pragma unroll
    for (int i = 0; i < 4; i++)
#pragma unroll
        for (int j = 0; j < 4; j++) acc[i][j] = 0.f;

    int k0base = z * KS;
    for (int k0 = k0base; k0 < k0base + KS; k0 += 16) {
#pragma unroll
        for (int l = 0; l < 4; l++) {
            int e = tid + l * 256;
            int rr = e >> 4, kk = e & 15;
            As[kk][rr] = h[(size_t)(row0 + rr) * C_ + k0 + kk];
        }
#pragma unroll
        for (int l = 0; l < 4; l++) {
            int e = tid + l * 256;
            int kk = e >> 6, cc = e & 63;
            int gc = col0 + cc, gk = k0 + kk;
            float v = 0.f;
            if (gc < PR)            v = Wr[(size_t)gk * PR + gc];
            else if (gc < PR + PWW) v = Ww[(size_t)gk * PWW + (gc - PR)];
            else if (gc < PTOT)     v = Wout[(size_t)gk * OUT_ + (gc - PR - PWW)];
            Bs[kk][cc] = v;
        }
        __syncthreads();
#pragma unroll
        for (int kk = 0; kk < 16; kk++) {
            float4 a4 = *(const float4*)&As[kk][ty * 4];
            float4 b4 = *(const float4*)&Bs[kk][tx * 4];
            float av[4] = {a4.x, a4.y, a4.z, a4.w};
            float bv[4] = {b4.x, b4.y, b4.z, b4.w};
#pragma unroll
            for (int i = 0; i < 4; i++)
#pragma unroll
                for (int j = 0; j < 4; j++) acc[i][j] += av[i] * bv[j];
        }
        __syncthreads();
    }
    float* Pp = Ppart + (size_t)z * B_ * PTOT;
#pragma unroll
    for (int i = 0; i < 4; i++)
#pragma unroll
        for (int j = 0; j < 4; j++) {
            int gc = col0 + tx * 4 + j;
            if (gc < PTOT)
                Pp[(size_t)(row0 + ty * 4 + i) * PTOT + gc] = acc[i][j];
        }
}

// ---------------- fused addressing + r_new + mem update + out ----------------
struct __align__(16) AddrShared {
    float Psum[PTOT];   // p (both heads) + e + a + out, bias included
    float red[256];
    float wsh[256];
    float scal[8];
    float ea[256];
};

// validated addressing math; psrc points into LDS Psum
__device__ __forceinline__ void compute_w_lds(
    AddrShared& sm, const float* psrc,
    const float* __restrict__ mem, float* __restrict__ wglob, int b)
{
    int tid = threadIdx.x;
    float kq = 0.f;
    if (tid < M_) { float kv = psrc[tid]; kq = kv * kv; }
    sm.red[tid] = kq;
    __syncthreads();
    for (int s = 128; s > 0; s >>= 1) { if (tid < s) sm.red[tid] += sm.red[tid + s]; __syncthreads(); }
    if (tid == 0) {
        sm.scal[0] = sqrtf(sm.red[0]);                 // ||k||
        sm.scal[1] = softplusf(psrc[M_]);              // beta
        sm.scal[2] = sigmoidf(psrc[M_ + 1]);           // g
        float a0 = psrc[M_ + 2], a1 = psrc[M_ + 3], a2 = psrc[M_ + 4];
        float mx = fmaxf(a0, fmaxf(a1, a2));
        float e0 = expf(a0 - mx), e1 = expf(a1 - mx), e2 = expf(a2 - mx);
        float inv = 1.f / (e0 + e1 + e2);
        sm.scal[3] = e0 * inv; sm.scal[4] = e1 * inv; sm.scal[5] = e2 * inv;  // s
        sm.scal[6] = 1.f + softplusf(psrc[M_ + 5]);    // gamma
    }
    __syncthreads();
    // cosine similarity, one memory row n per thread
    const float* mrow = mem + ((size_t)b * N_ + tid) * M_;
    float dot = 0.f, nrm = 0.f;
#pragma unroll 8
    for (int m = 0; m < M_; m += 4) {
        float4 v = *(const float4*)&mrow[m];
        float4 kk = *(const float4*)&psrc[m];
        dot += v.x * kk.x + v.y * kk.y + v.z * kk.z + v.w * kk.w;
        nrm += v.x * v.x + v.y * v.y + v.z * v.z + v.w * v.w;
    }
    float sim = dot / (sm.scal[0] * sqrtf(nrm) + EPSF);
    float zz = sm.scal[1] * sim;
    // softmax over n
    sm.red[tid] = zz;
    __syncthreads();
    for (int s = 128; s > 0; s >>= 1) { if (tid < s) sm.red[tid] = fmaxf(sm.red[tid], sm.red[tid + s]); __syncthreads(); }
    float mx = sm.red[0];
    __syncthreads();
    float ez = expf(zz - mx);
    sm.red[tid] = ez;
    __syncthreads();
    for (int s = 128; s > 0; s >>= 1) { if (tid < s) sm.red[tid] += sm.red[tid + s]; __syncthreads(); }
    float wc = ez / sm.red[0];
    float g = sm.scal[2];
    float wgv = g * wc + (1.f - g) * wglob[(size_t)b * N_ + tid];
    __syncthreads();
    sm.wsh[tid] = wgv;
    __syncthreads();
    // wt[n] = s0*wg[n+1] + s1*wg[n] + s2*wg[n-1] (circular)
    float wt = sm.scal[3] * sm.wsh[(tid + 1) & (N_ - 1)]
             + sm.scal[4] * wgv
             + sm.scal[5] * sm.wsh[(tid + N_ - 1) & (N_ - 1)];
    float wp = powf(wt + EPSF, sm.scal[6]);
    sm.red[tid] = wp;
    __syncthreads();
    for (int s = 128; s > 0; s >>= 1) { if (tid < s) sm.red[tid] += sm.red[tid + s]; __syncthreads(); }
    float wfin = wp / sm.red[0];
    wglob[(size_t)b * N_ + tid] = wfin;
    __syncthreads();
    sm.wsh[tid] = wfin;
    __syncthreads();
}

__global__ __launch_bounds__(256) void addr_fused(
    const float* __restrict__ Ppart, const float* __restrict__ bcat,
    float* __restrict__ mem, float* __restrict__ w_r, float* __restrict__ w_w,
    float* __restrict__ r_out, float* __restrict__ out, int t)
{
    __shared__ AddrShared sm;
    int b = blockIdx.x, tid = threadIdx.x;

    // Psum = bias + sum of 4 split-K partials (all PTOT cols)
    for (int c = tid; c < PTOT; c += 256) {
        float v = bcat[c];
#pragma unroll
        for (int s = 0; s < 4; s++)
            v += Ppart[(size_t)s * B_ * PTOT + (size_t)b * PTOT + c];
        sm.Psum[c] = v;
    }
    __syncthreads();

    // ---- read head: w_r, then r_new from OLD mem ----
    compute_w_lds(sm, sm.Psum, mem, w_r, b);
    {
        int m = tid & (M_ - 1), half = tid >> 7;
        float acc = 0.f;
        const float* mb = mem + (size_t)b * N_ * M_;
        int n0 = half * 128;
        for (int n = n0; n < n0 + 128; n++) acc += sm.wsh[n] * mb[n * M_ + m];
        sm.red[tid] = acc;
        __syncthreads();
        if (tid < 128) r_out[b * M_ + tid] = sm.red[tid] + sm.red[tid + 128];
        __syncthreads();
    }

    // ---- write head: w_w (uses OLD mem), then erase/add update ----
    compute_w_lds(sm, sm.Psum + PR, mem, w_w, b);
    if (tid < M_) {
        sm.ea[tid]       = sigmoidf(sm.Psum[2 * PR + tid]);        // e
        sm.ea[M_ + tid]  = tanhf(sm.Psum[2 * PR + M_ + tid]);      // a
    }
    __syncthreads();
    float4* mb4 = (float4*)(mem + (size_t)b * N_ * M_);
    for (int idx = tid; idx < N_ * M_ / 4; idx += 256) {
        int n = idx >> 5;               // 32 float4 per row
        int mq = (idx & 31) * 4;
        float wv = sm.wsh[n];
        float4 v = mb4[idx];
        float4 e4 = *(const float4*)&sm.ea[mq];
        float4 a4 = *(const float4*)&sm.ea[M_ + mq];
        v.x = v.x * (1.f - wv * e4.x) + wv * a4.x;
        v.y = v.y * (1.f - wv * e4.y) + wv * a4.y;
        v.z = v.z * (1.f - wv * e4.z) + wv * a4.z;
        v.w = v.w * (1.f - wv * e4.w) + wv * a4.w;
        mb4[idx] = v;
    }

    // ---- out = Psum cols [524, 1036) ----
    for (int j = tid; j < OUT_; j += 256)
        out[((size_t)b * T_ + t) * OUT_ + j] = sm.Psum[PR + PWW + j];
}

// ---------------- launch ----------------
static const float* by_size(void* const* d_in, const int* in_sizes, int n_in,
                            long long want, int fallback)
{
    for (int i = 0; i < n_in; i++)
        if ((long long)in_sizes[i] == want) return (const float*)d_in[i];
    return (const float*)d_in[fallback];
}

extern "C" void kernel_launch(void* const* d_in, const int* in_sizes, int n_in,
                              void* d_out, int out_size, void* d_ws, size_t ws_size,
                              hipStream_t stream)
{
    const float* x         = by_size(d_in, in_sizes, n_in, (long long)B_ * T_ * IN_, 0);
    const float* Wc        = by_size(d_in, in_sizes, n_in, (long long)(M_ + IN_) * C_, 1);
    const float* bc        = by_size(d_in, in_sizes, n_in, C_, 2);
    const float* Wout      = by_size(d_in, in_sizes, n_in, (long long)C_ * OUT_, 3);
    const float* bout      = by_size(d_in, in_sizes, n_in, OUT_, 4);
    const float* Wr        = by_size(d_in, in_sizes, n_in, (long long)C_ * PR, 5);
    const float* br        = by_size(d_in, in_sizes, n_in, PR, 6);
    const float* Ww        = by_size(d_in, in_sizes, n_in, (long long)C_ * PWW, 7);
    const float* bw        = by_size(d_in, in_sizes, n_in, PWW, 8);
    const float* mem_init  = by_size(d_in, in_sizes, n_in, N_ * M_, 9);
    const float* read_init = by_size(d_in, in_sizes, n_in, M_, 10);
    float* out = (float*)d_out;

    char* p = (char*)d_ws;
    auto alloc = [&](size_t bytes) -> void* {
        void* q = (void*)p;
        p += (bytes + 255) & ~(size_t)255;
        return q;
    };
    float* mem   = (float*)alloc(sizeof(float) * B_ * N_ * M_);
    float* r     = (float*)alloc(sizeof(float) * B_ * M_);
    float* w_r   = (float*)alloc(sizeof(float) * B_ * N_);
    float* w_w   = (float*)alloc(sizeof(float) * B_ * N_);
    float* h     = (float*)alloc(sizeof(float) * B_ * C_);
    float* Hpart = (float*)alloc(sizeof(float) * 4 * B_ * C_);
    float* Ppart = (float*)alloc(sizeof(float) * 4 * B_ * PTOT);
    float* bcat  = (float*)alloc(sizeof(float) * PTOT);

    init_state<<<2048, 256, 0, stream>>>(mem, w_r, w_w, r, bcat,
                                         mem_init, read_init, br, bw, bout);

    for (int t = 0; t < T_; t++) {
        gemm_h_tiled<<<dim3(32, 2, 4), 256, 0, stream>>>(r, x, Wc, Hpart, t);
        finalize_h<<<(B_ * C_) / 256, 256, 0, stream>>>(Hpart, bc, h);
        gemm_p_tiled<<<dim3(17, 2, 4), 256, 0, stream>>>(h, Wr, Ww, Wout, Ppart);
        addr_fused<<<128, 256, 0, stream>>>(Ppart, bcat, mem, w_r, w_w, r, out, t);
    }
}